// Round 10
// baseline (304.594 us; speedup 1.0000x reference)
//
#include <hip/hip_runtime.h>

#define KK 27
#define PT 14   // packed taps per phase (27 taps -> 14 pairs, last half dummy/zero)

typedef short bf16x8 __attribute__((ext_vector_type(8)));   // 8 bf16 in 4 VGPRs
typedef float f32x4  __attribute__((ext_vector_type(4)));

#define SC_AGENT __HIP_MEMORY_SCOPE_AGENT

__device__ inline unsigned short f2bf(float f) {            // RNE fp32 -> bf16
    unsigned u = __float_as_uint(f);
    unsigned r = u + 0x7fffu + ((u >> 16) & 1u);
    return (unsigned short)(r >> 16);
}
__device__ inline unsigned packbf(float a, float b) {       // two bf16 in one uint
    return (unsigned)f2bf(a) | ((unsigned)f2bf(b) << 16);
}

// Fence-FREE grid rendezvous. R8 (acquire per poll) = 786us; R9 (acquire+release
// per block) = 205us -- agent fences are whole-L2 wb/inv on non-coherent XCDs and
// ~100 of them per XCD serialize right as the next phase starts. Here ALL
// cross-phase shared data is written with agent-scope relaxed ATOMIC stores
// (write-through past L2 to the LLC), so the barrier itself needs no cache
// maintenance: __syncthreads drains vmcnt (stores acked at LLC) and is a full
// compiler barrier; arrival/flag are LLC atomics.
__device__ __forceinline__ void rendezvous(int* cnt, int* flag) {
    __syncthreads();
    if (threadIdx.x == 0) {
        if (__hip_atomic_fetch_add(cnt, 1, __ATOMIC_RELAXED, SC_AGENT)
            == (int)gridDim.x - 1) {
            __hip_atomic_store(flag, 1, __ATOMIC_RELAXED, SC_AGENT);
        } else {
            while (__hip_atomic_load(flag, __ATOMIC_RELAXED, SC_AGENT) == 0)
                __builtin_amdgcn_s_sleep(16);
        }
    }
    __syncthreads();
}

// One cin-half conv pass: 14 packed taps (quads 0,1 -> tap 2t; quads 2,3 -> tap
// 2t+1), depth-2 pipeline, 2 node streams. Correctness of this body was verified
// end-to-end in round 5 (passed, absmax 0.03125). Invalid/dummy lanes gather the
// all-zero row N; dummy tap 27 has zero weights.
__device__ __forceinline__ void conv_phase(const unsigned short* __restrict__ xp,
                                           const unsigned short* __restrict__ wp,
                                           const int* __restrict__ neigh,
                                           long nb0, long nb1, bool v0, bool v1,
                                           int r16, int quad, int tapsel, int off8,
                                           int N, f32x4& acc00, f32x4& acc01,
                                           f32x4& acc10, f32x4& acc11) {
    auto ldidx = [&](long nb, bool v, int kq) -> int {
        int kc = (kq < KK) ? kq : (KK - 1);
        int j  = __builtin_nontemporal_load(neigh + nb + kc);
        return (v && kq < KK) ? j : N;
    };
    int ia = ldidx(nb0, v0, tapsel);
    int ib = ldidx(nb1, v1, tapsel);
    int ja = ldidx(nb0, v0, 2 + tapsel);
    int jb = ldidx(nb1, v1, 2 + tapsel);

    bf16x8 a0 = *(const bf16x8*)(xp + (long)ia * 16 + off8);
    bf16x8 a1 = *(const bf16x8*)(xp + (long)ib * 16 + off8);
    bf16x8 b0 = *(const bf16x8*)(wp + r16 * 32 + quad * 8);
    bf16x8 b1 = *(const bf16x8*)(wp + (16 + r16) * 32 + quad * 8);

#pragma unroll 1
    for (int t = 0; t < PT; ++t) {
        bf16x8 na0, na1, pb0, pb1;
        if (t < PT - 1) {
            na0 = *(const bf16x8*)(xp + (long)ja * 16 + off8);
            na1 = *(const bf16x8*)(xp + (long)jb * 16 + off8);
            const unsigned short* wn = wp + (t + 1) * 1024;
            pb0 = *(const bf16x8*)(wn + r16 * 32 + quad * 8);
            pb1 = *(const bf16x8*)(wn + (16 + r16) * 32 + quad * 8);
            ja = ldidx(nb0, v0, 2 * (t + 2) + tapsel);
            jb = ldidx(nb1, v1, 2 * (t + 2) + tapsel);
        }
        acc00 = __builtin_amdgcn_mfma_f32_16x16x32_bf16(a0, b0, acc00, 0, 0, 0);
        acc01 = __builtin_amdgcn_mfma_f32_16x16x32_bf16(a0, b1, acc01, 0, 0, 0);
        acc10 = __builtin_amdgcn_mfma_f32_16x16x32_bf16(a1, b0, acc10, 0, 0, 0);
        acc11 = __builtin_amdgcn_mfma_f32_16x16x32_bf16(a1, b1, acc11, 0, 0, 0);
        if (t < PT - 1) {
            a0 = na0; a1 = na1; b0 = pb0; b1 = pb1;
        }
    }
}

// Fused: prep -> bar -> conv(xLo) -> bar -> conv(xHi) -> epilogue -> bar -> stats+norm.
// The mid-conv barrier gives TEMPORAL cin-phasing: each 3.2MB half is L2-resident
// per XCD during its phase (the round-5 attempt failed because waves drifted across
// phases in one launch; registers now carry the accumulators across the barrier).
__global__ __launch_bounds__(256, 4) void fused_k(const float* __restrict__ in,
                                                  const int* __restrict__ neigh,
                                                  const float* __restrict__ w,
                                                  const float* __restrict__ gamma,
                                                  const float* __restrict__ beta,
                                                  float* __restrict__ y,       // out [32][N]
                                                  unsigned* __restrict__ xLoU, // (N+1)x8 uints
                                                  unsigned* __restrict__ xHiU,
                                                  unsigned short* __restrict__ wP0,
                                                  unsigned short* __restrict__ wP1,
                                                  float* __restrict__ tot,     // [32][64]
                                                  int* __restrict__ bar,       // pre-zeroed
                                                  int N) {
    __shared__ float lds[4 * 32 * 33];   // prep tile / conv ct[4] / stats sums

    const int tid   = threadIdx.x;
    const int nxblk = (N + 31) / 32;

    // ===== Phase P: prep (grid-stride; x-halves, packed weights, tot zero) =====
    {
        float (*tile)[33] = reinterpret_cast<float(*)[33]>(lds);
        unsigned* wP0U = (unsigned*)wP0;
        unsigned* wP1U = (unsigned*)wP1;
        for (int b = blockIdx.x; b < nxblk + PT; b += (int)gridDim.x) {
            if (b < nxblk) {
                int n0t = b * 32;
                int tx = tid & 31;
                int ty = tid >> 5;
                __syncthreads();
#pragma unroll
                for (int c = ty; c < 32; c += 8) {
                    int n = n0t + tx;
                    tile[c][tx] = (n < N) ? in[(long)c * N + n] : 0.f;
                }
                __syncthreads();
#pragma unroll
                for (int rep = 0; rep < 2; ++rep) {
                    int idx = rep * 256 + tid;       // 512 uints per 32-node tile
                    int n  = idx >> 4;               // node within tile
                    int q  = idx & 15;               // uint slot: 0..7 lo, 8..15 hi
                    int hi = q >> 3;
                    int qq = q & 7;
                    int c0 = hi * 16 + 2 * qq;
                    unsigned val = packbf(tile[c0][n], tile[c0 + 1][n]);
                    int gn = n0t + n;
                    if (gn < N) {
                        unsigned* dst = hi ? xHiU : xLoU;
                        __hip_atomic_store(&dst[(long)gn * 8 + qq], val,
                                           __ATOMIC_RELAXED, SC_AGENT);
                    }
                }
                if (b == 0 && tid < 16) {            // zero row N (both halves)
                    unsigned* dst = (tid >> 3) ? xHiU : xLoU;
                    __hip_atomic_store(&dst[(long)N * 8 + (tid & 7)], 0u,
                                       __ATOMIC_RELAXED, SC_AGENT);
                }
            } else {
                int t = b - nxblk;                   // 0..PT-1
#pragma unroll
                for (int rep = 0; rep < 2; ++rep) {
                    int i = rep * 256 + tid;         // 512 uint pairs per plane
                    int cout = i >> 4, kp = i & 15;
                    int tap = 2 * t + (kp >> 3);
                    int cb  = 2 * (kp & 7);
                    unsigned lo = 0, hi = 0;
                    if (tap < KK) {
                        lo = packbf(w[tap * 1024 + cb * 32 + cout],
                                    w[tap * 1024 + (cb + 1) * 32 + cout]);
                        hi = packbf(w[tap * 1024 + (cb + 16) * 32 + cout],
                                    w[tap * 1024 + (cb + 17) * 32 + cout]);
                    }
                    __hip_atomic_store(&wP0U[t * 512 + cout * 16 + kp], lo,
                                       __ATOMIC_RELAXED, SC_AGENT);
                    __hip_atomic_store(&wP1U[t * 512 + cout * 16 + kp], hi,
                                       __ATOMIC_RELAXED, SC_AGENT);
                }
                if (t == 0) {
                    for (int i = tid; i < 32 * 64; i += 256)
                        __hip_atomic_store(&tot[i], 0.f, __ATOMIC_RELAXED, SC_AGENT);
                }
            }
        }
    }
    int bark = 0;
    rendezvous(&bar[2 * bark], &bar[2 * bark + 1]); ++bark;

    // ===== Phase C: conv, cin-split with temporal phasing =====
    {
        float (*ct)[32][33] = reinterpret_cast<float(*)[32][33]>(lds);
        const int L      = tid & 63;
        const int wv     = tid >> 6;
        const int r16    = L & 15;
        const int quad   = L >> 4;
        const int tapsel = quad >> 1;
        const int off8   = (quad & 1) * 8;
        const int ntiles = (N + 31) / 32;
        const int step   = (int)gridDim.x * 4;
        const int iters  = (ntiles + step - 1) / step;   // uniform across blocks

        for (int it = 0; it < iters; ++it) {
            const int tile_id = blockIdx.x * 4 + wv + it * step;
            const int base = tile_id * 32;
            const int n0 = base + r16;
            const int n1 = base + 16 + r16;
            const bool v0 = (n0 < N), v1 = (n1 < N);
            const long nb0 = (long)(v0 ? n0 : 0) * KK;
            const long nb1 = (long)(v1 ? n1 : 0) * KK;

            f32x4 acc00 = {0.f, 0.f, 0.f, 0.f};
            f32x4 acc01 = acc00, acc10 = acc00, acc11 = acc00;

            conv_phase((const unsigned short*)xLoU, wP0, neigh, nb0, nb1, v0, v1,
                       r16, quad, tapsel, off8, N, acc00, acc01, acc10, acc11);

            rendezvous(&bar[2 * bark], &bar[2 * bark + 1]); ++bark;   // phase flip

            conv_phase((const unsigned short*)xHiU, wP1, neigh, nb0, nb1, v0, v1,
                       r16, quad, tapsel, off8, N, acc00, acc01, acc10, acc11);

            // BN partials (zero for invalid waves), striped atomics
            float s0 = 0.f, q0 = 0.f, s1 = 0.f, q1 = 0.f;
#pragma unroll
            for (int r = 0; r < 4; ++r) {
                s0 += acc00[r] + acc10[r];
                q0 += acc00[r] * acc00[r] + acc10[r] * acc10[r];
                s1 += acc01[r] + acc11[r];
                q1 += acc01[r] * acc01[r] + acc11[r] * acc11[r];
            }
#pragma unroll
            for (int off = 16; off < 64; off <<= 1) {
                s0 += __shfl_xor(s0, off, 64);
                q0 += __shfl_xor(q0, off, 64);
                s1 += __shfl_xor(s1, off, 64);
                q1 += __shfl_xor(q1, off, 64);
            }
            const int stripe = tile_id & 31;
            if (L < 16) {
                float* tb = tot + stripe * 64;
                atomicAdd(&tb[L],      s0);
                atomicAdd(&tb[L + 16], s1);
                atomicAdd(&tb[L + 32], q0);
                atomicAdd(&tb[L + 48], q1);
            }

            // per-wave LDS transpose -> coalesced agent-scope y stores
#pragma unroll
            for (int r = 0; r < 4; ++r) {
                ct[wv][quad * 4 + r][r16]           = acc00[r];
                ct[wv][quad * 4 + r][16 + r16]      = acc01[r];
                ct[wv][16 + quad * 4 + r][r16]      = acc10[r];
                ct[wv][16 + quad * 4 + r][16 + r16] = acc11[r];
            }
            const int node = L & 31;
            const int half = L >> 5;
            const int gn = base + node;
            if (gn < N) {
#pragma unroll
                for (int i = 0; i < 16; ++i) {
                    const int cout = i * 2 + half;
                    __hip_atomic_store(&y[(long)cout * N + gn], ct[wv][node][cout],
                                       __ATOMIC_RELAXED, SC_AGENT);
                }
            }
        }
    }
    rendezvous(&bar[2 * bark], &bar[2 * bark + 1]);

    // ===== Phase S: reduce striped sums (atomic loads -- tot's truth is at LLC) =====
    if (tid < 64) {
        float v = 0.f;
#pragma unroll
        for (int s = 0; s < 32; ++s)
            v += __hip_atomic_load(&tot[s * 64 + tid], __ATOMIC_RELAXED, SC_AGENT);
        lds[tid] = v;   // [0..31] sum, [32..63] sumsq
    }
    __syncthreads();

    // ===== Phase N: normalize y in place (grid-stride, d-major) =====
    {
        const long N4 = ((long)N + 3) >> 2;
        const long items = 32 * N4;
        const float invN = 1.f / (float)N;
        for (long it = (long)blockIdx.x * 256 + tid; it < items;
             it += (long)gridDim.x * 256) {
            const int  d  = (int)(it / N4);
            const long i4 = it - (long)d * N4;
            const float mean = lds[d] * invN;
            const float var  = lds[32 + d] * invN - mean * mean;
            const float sc   = gamma[d] * rsqrtf(var + 1e-3f);
            const float sh   = beta[d] - mean * sc;
            const long base = i4 * 4;
            float* yp = y + (long)d * N + base;
            if (base + 3 < N) {
                float4 v = *(float4*)yp;
                v.x = fmaf(v.x, sc, sh);
                v.y = fmaf(v.y, sc, sh);
                v.z = fmaf(v.z, sc, sh);
                v.w = fmaf(v.w, sc, sh);
                *(float4*)yp = v;
            } else if (base < N) {
                for (long t = base; t < N; ++t)
                    y[(long)d * N + t] = fmaf(y[(long)d * N + t], sc, sh);
            }
        }
    }
}

// ---- launcher: memset barrier slab + ONE regular launch (graph-capture safe) ----
extern "C" void kernel_launch(void* const* d_in, const int* in_sizes, int n_in,
                              void* d_out, int out_size, void* d_ws, size_t ws_size,
                              hipStream_t stream) {
    const float* data_in = (const float*)d_in[0];
    const int*   neigh   = (const int*)d_in[1];
    const float* weight  = (const float*)d_in[2];
    const float* gamma   = (const float*)d_in[3];
    const float* beta    = (const float*)d_in[4];
    float* out = (float*)d_out;

    int N = in_sizes[1] / KK;
    const int ntiles = (N + 31) / 32;
    int nblk = (ntiles + 3) / 4;        // 782 @ N=100k: all blocks co-resident
    if (nblk > 1024) nblk = 1024;       // grid-stride + per-iter barriers stay correct
    if (nblk < 1) nblk = 1;

    char* ws = (char*)d_ws;
    unsigned* xLoU = (unsigned*)ws;                          // (N+1)*8 uints
    unsigned* xHiU = xLoU + (size_t)(N + 1) * 8;
    unsigned short* wP0 = (unsigned short*)(xHiU + (size_t)(N + 1) * 8);  // PT*1024
    unsigned short* wP1 = wP0 + PT * 1024;
    float* tot = (float*)(wP1 + PT * 1024);                  // 2048 floats
    int*   bar = (int*)(tot + 2048);                         // 64 ints (barrier slab)

    hipMemsetAsync(bar, 0, 64 * sizeof(int), stream);
    fused_k<<<dim3(nblk), dim3(256), 0, stream>>>(data_in, neigh, weight, gamma, beta,
                                                  out, xLoU, xHiU, wP0, wP1, tot, bar, N);
}

// Round 11
// 167.275 us; speedup vs baseline: 1.8209x; 1.8209x over previous
//
#include <hip/hip_runtime.h>

#define KK 27
#define PT 14   // packed taps per phase (27 taps -> 14 pairs, last half dummy/zero)
#define SC_AGENT __HIP_MEMORY_SCOPE_AGENT

typedef short bf16x8 __attribute__((ext_vector_type(8)));   // 8 bf16 in 4 VGPRs
typedef float f32x4  __attribute__((ext_vector_type(4)));

__device__ inline unsigned short f2bf(float f) {            // RNE fp32 -> bf16
    unsigned u = __float_as_uint(f);
    unsigned r = u + 0x7fffu + ((u >> 16) & 1u);
    return (unsigned short)(r >> 16);
}

// ---- Launch 1: prep (R5-verified body) + zero tot + zero barrier slabs ----
// x [32][N] fp32 -> xLo[N+1][16] (cin 0..15) / xHi[N+1][16] (cin 16..31) bf16;
// row N all-zero. Packed weights wP0/wP1[t][cout=32][k32] (tap 2t | tap 2t+1),
// tap 27 zero-filled. Plain stores: kernel-end L2 flush publishes everything.
__global__ __launch_bounds__(256) void prep_k(const float* __restrict__ in,
                                              const float* __restrict__ w,
                                              unsigned short* __restrict__ xLo,
                                              unsigned short* __restrict__ xHi,
                                              unsigned short* __restrict__ wP0,
                                              unsigned short* __restrict__ wP1,
                                              float* __restrict__ tot,
                                              int* __restrict__ bar,
                                              int N, int nxblk) {
    __shared__ float tile[32][33];
    const int b = blockIdx.x;
    if (b < nxblk) {
        int n0 = b * 32;
        int tx = threadIdx.x & 31;
        int ty = threadIdx.x >> 5;
#pragma unroll
        for (int c = ty; c < 32; c += 8) {
            int n = n0 + tx;
            tile[c][tx] = (n < N) ? in[(long)c * N + n] : 0.f;
        }
        __syncthreads();
#pragma unroll
        for (int nn = ty; nn < 32; nn += 8) {
            int n = n0 + nn;
            if (n < N) {
                unsigned short v = f2bf(tile[tx][nn]);
                if (tx < 16) xLo[(long)n * 16 + tx]        = v;
                else         xHi[(long)n * 16 + (tx - 16)] = v;
            }
        }
        if (b == 0 && threadIdx.x < 32) {
            int t = threadIdx.x;
            if (t < 16) xLo[(long)N * 16 + t]        = 0;
            else        xHi[(long)N * 16 + (t - 16)] = 0;
        }
    } else {
        int t = b - nxblk;                  // 0..PT-1
        for (int i = threadIdx.x; i < 1024; i += 256) {
            int cout = i >> 5, k32 = i & 31;
            int tap = 2 * t + (k32 >> 4);
            int c   = k32 & 15;
            unsigned short lo = 0, hi = 0;
            if (tap < KK) {
                lo = f2bf(w[tap * 1024 + c * 32 + cout]);
                hi = f2bf(w[tap * 1024 + (c + 16) * 32 + cout]);
            }
            wP0[t * 1024 + cout * 32 + k32] = lo;
            wP1[t * 1024 + cout * 32 + k32] = hi;
        }
        if (t == 0) {
            for (int i = threadIdx.x; i < 32 * 64; i += 256) tot[i] = 0.f;
            for (int i = threadIdx.x; i < 16 * 1024; i += 256) bar[i] = 0;  // 16 slabs
        }
    }
}

// ---- Decentralized one-shot rendezvous (slab = 1024 ints / 4KB) ----
// Layout: group cnt g at [g*16] (64B apart), global cnt at [256], flag g at [512+g*16].
// 16-way arrival spreads the single-line RMW hot-spot of R8-R10 (782 RMWs on one
// line + ~1800 polls/us on one flag congested the fabric the workers' gathers use);
// s_sleep(64) (~1.7us) cuts per-spinner poll rate ~4x on top. No fences: rendezvous A
// exchanges nothing (pure phasing); rendezvous B's payload (tot) travels via LLC atomics.
__device__ __forceinline__ void rendezvous(int* slab, int nblk) {
    __syncthreads();
    if (threadIdx.x == 0) {
        const int g = blockIdx.x & 15;
        const int expect = ((nblk - 1 - g) >> 4) + 1;   // blocks with bid%16==g
        int* flag = slab + 512 + g * 16;
        bool release = false;
        if (__hip_atomic_fetch_add(slab + g * 16, 1, __ATOMIC_RELAXED, SC_AGENT)
            == expect - 1) {                            // group leader
            if (__hip_atomic_fetch_add(slab + 256, 1, __ATOMIC_RELAXED, SC_AGENT)
                == 15) release = true;                  // last leader
        }
        if (release) {
#pragma unroll
            for (int i = 0; i < 16; ++i)
                __hip_atomic_store(slab + 512 + i * 16, 1, __ATOMIC_RELAXED, SC_AGENT);
        } else {
            while (__hip_atomic_load(flag, __ATOMIC_RELAXED, SC_AGENT) == 0)
                __builtin_amdgcn_s_sleep(64);
        }
    }
    __syncthreads();
}

// ---- One cin-half conv pass (R5-verified): 14 packed taps, depth-2, 2 streams ----
__device__ __forceinline__ void conv_phase(const unsigned short* __restrict__ xp,
                                           const unsigned short* __restrict__ wp,
                                           const int* __restrict__ neigh,
                                           long nb0, long nb1, bool v0, bool v1,
                                           int r16, int quad, int tapsel, int off8,
                                           int N, f32x4& acc00, f32x4& acc01,
                                           f32x4& acc10, f32x4& acc11) {
    auto ldidx = [&](long nb, bool v, int kq) -> int {
        int kc = (kq < KK) ? kq : (KK - 1);
        int j  = __builtin_nontemporal_load(neigh + nb + kc);
        return (v && kq < KK) ? j : N;
    };
    int ia = ldidx(nb0, v0, tapsel);
    int ib = ldidx(nb1, v1, tapsel);
    int ja = ldidx(nb0, v0, 2 + tapsel);
    int jb = ldidx(nb1, v1, 2 + tapsel);

    bf16x8 a0 = *(const bf16x8*)(xp + (long)ia * 16 + off8);
    bf16x8 a1 = *(const bf16x8*)(xp + (long)ib * 16 + off8);
    bf16x8 b0 = *(const bf16x8*)(wp + r16 * 32 + quad * 8);
    bf16x8 b1 = *(const bf16x8*)(wp + (16 + r16) * 32 + quad * 8);

#pragma unroll 1
    for (int t = 0; t < PT; ++t) {
        bf16x8 na0, na1, pb0, pb1;
        if (t < PT - 1) {
            na0 = *(const bf16x8*)(xp + (long)ja * 16 + off8);
            na1 = *(const bf16x8*)(xp + (long)jb * 16 + off8);
            const unsigned short* wn = wp + (t + 1) * 1024;
            pb0 = *(const bf16x8*)(wn + r16 * 32 + quad * 8);
            pb1 = *(const bf16x8*)(wn + (16 + r16) * 32 + quad * 8);
            ja = ldidx(nb0, v0, 2 * (t + 2) + tapsel);
            jb = ldidx(nb1, v1, 2 * (t + 2) + tapsel);
        }
        acc00 = __builtin_amdgcn_mfma_f32_16x16x32_bf16(a0, b0, acc00, 0, 0, 0);
        acc01 = __builtin_amdgcn_mfma_f32_16x16x32_bf16(a0, b1, acc01, 0, 0, 0);
        acc10 = __builtin_amdgcn_mfma_f32_16x16x32_bf16(a1, b0, acc10, 0, 0, 0);
        acc11 = __builtin_amdgcn_mfma_f32_16x16x32_bf16(a1, b1, acc11, 0, 0, 0);
        if (t < PT - 1) {
            a0 = na0; a1 = na1; b0 = pb0; b1 = pb1;
        }
    }
}

// ---- Launch 2: conv-lo | rdvA | conv-hi + BN + y | rdvB | stats + SELF-norm ----
// Temporal cin-phasing: each 3.2MB x-half is L2-resident during its phase (R10
// proved FETCH 119->75MB). Self-norm: each block normalizes exactly the y region
// it wrote -> reads hit its own XCD's dirty L2, no fences / write-through needed.
__global__ __launch_bounds__(256, 4) void convnorm_k(const unsigned short* __restrict__ xLo,
                                                     const unsigned short* __restrict__ xHi,
                                                     const int* __restrict__ neigh,
                                                     const unsigned short* __restrict__ wP0,
                                                     const unsigned short* __restrict__ wP1,
                                                     const float* __restrict__ gamma,
                                                     const float* __restrict__ beta,
                                                     float* __restrict__ y,    // [32][N]
                                                     float* __restrict__ tot,  // [32][64]
                                                     int* __restrict__ bar,    // 16 slabs
                                                     int N) {
    __shared__ float ct[4][32][33];   // per-wave transpose slices; reused for stats

    const int tid    = threadIdx.x;
    const int L      = tid & 63;
    const int wv     = tid >> 6;
    const int r16    = L & 15;
    const int quad   = L >> 4;
    const int tapsel = quad >> 1;
    const int off8   = (quad & 1) * 8;
    const int ntiles = (N + 31) / 32;
    const int step   = (int)gridDim.x * 4;
    const int iters  = (ntiles + step - 1) / step;   // uniform across blocks (1 @ N=100k)

    for (int it = 0; it < iters; ++it) {
        const int tile_id = blockIdx.x * 4 + wv + it * step;
        const int base = tile_id * 32;
        const int n0 = base + r16;
        const int n1 = base + 16 + r16;
        const bool v0 = (n0 < N), v1 = (n1 < N);
        const long nb0 = (long)(v0 ? n0 : 0) * KK;
        const long nb1 = (long)(v1 ? n1 : 0) * KK;

        f32x4 acc00 = {0.f, 0.f, 0.f, 0.f};
        f32x4 acc01 = acc00, acc10 = acc00, acc11 = acc00;

        conv_phase(xLo, wP0, neigh, nb0, nb1, v0, v1, r16, quad, tapsel, off8, N,
                   acc00, acc01, acc10, acc11);

        rendezvous(bar + it * 1024, (int)gridDim.x);   // phase flip (pure sync)

        conv_phase(xHi, wP1, neigh, nb0, nb1, v0, v1, r16, quad, tapsel, off8, N,
                   acc00, acc01, acc10, acc11);

        // BN partials over this wave's 32 nodes -> striped LLC atomics
        float s0 = 0.f, q0 = 0.f, s1 = 0.f, q1 = 0.f;
#pragma unroll
        for (int r = 0; r < 4; ++r) {
            s0 += acc00[r] + acc10[r];
            q0 += acc00[r] * acc00[r] + acc10[r] * acc10[r];
            s1 += acc01[r] + acc11[r];
            q1 += acc01[r] * acc01[r] + acc11[r] * acc11[r];
        }
#pragma unroll
        for (int off = 16; off < 64; off <<= 1) {
            s0 += __shfl_xor(s0, off, 64);
            q0 += __shfl_xor(q0, off, 64);
            s1 += __shfl_xor(s1, off, 64);
            q1 += __shfl_xor(q1, off, 64);
        }
        const int stripe = tile_id & 31;
        if (L < 16) {
            float* tb = tot + stripe * 64;
            atomicAdd(&tb[L],      s0);
            atomicAdd(&tb[L + 16], s1);
            atomicAdd(&tb[L + 32], q0);
            atomicAdd(&tb[L + 48], q1);
        }

        // per-wave LDS transpose -> y stores (nontemporal: keep x-half L2-resident;
        // self-norm read-back is same-XCD / LLC either way)
#pragma unroll
        for (int r = 0; r < 4; ++r) {
            ct[wv][quad * 4 + r][r16]           = acc00[r];
            ct[wv][quad * 4 + r][16 + r16]      = acc01[r];
            ct[wv][16 + quad * 4 + r][r16]      = acc10[r];
            ct[wv][16 + quad * 4 + r][16 + r16] = acc11[r];
        }
        const int node = L & 31;
        const int half = L >> 5;
        const int gn = base + node;
        if (gn < N) {
#pragma unroll
            for (int i = 0; i < 16; ++i) {
                const int cout = i * 2 + half;
                __builtin_nontemporal_store(ct[wv][node][cout], y + (long)cout * N + gn);
            }
        }
    }

    rendezvous(bar + 15 * 1024, (int)gridDim.x);       // all tot atomics done

    // stats: reduce 32 stripes via LLC atomic loads (truth lives at LLC)
    float* sums = (float*)ct;
    if (tid < 64) {
        float v = 0.f;
#pragma unroll
        for (int s = 0; s < 32; ++s)
            v += __hip_atomic_load(&tot[s * 64 + tid], __ATOMIC_RELAXED, SC_AGENT);
        sums[tid] = v;   // [0..31] sum, [32..63] sumsq
    }
    __syncthreads();

    // SELF-norm: block normalizes its own written regions [rb, rb+128)
    {
        const float invN = 1.f / (float)N;
        const int cout = tid >> 3;                     // 8 threads per cout
        const int l8   = tid & 7;
        const float mean = sums[cout] * invN;
        const float var  = sums[32 + cout] * invN - mean * mean;
        const float sc   = gamma[cout] * rsqrtf(var + 1e-3f);
        const float sh   = beta[cout] - mean * sc;
        for (int it = 0; it < iters; ++it) {
            const long rb = ((long)blockIdx.x * 4 + (long)it * step) * 32;
#pragma unroll
            for (int j = 0; j < 4; ++j) {
                const long nb = rb + l8 * 16 + j * 4;
                float* yp = y + (long)cout * N + nb;
                if (nb + 3 < N) {
                    float4 v = *(float4*)yp;
                    v.x = fmaf(v.x, sc, sh);
                    v.y = fmaf(v.y, sc, sh);
                    v.z = fmaf(v.z, sc, sh);
                    v.w = fmaf(v.w, sc, sh);
                    *(float4*)yp = v;
                } else if (nb < N) {
                    for (long t = nb; t < N; ++t)
                        y[(long)cout * N + t] = fmaf(y[(long)cout * N + t], sc, sh);
                }
            }
        }
    }
}

// ---- launcher: TWO regular launches, no memset (prep zeroes tot + barrier slabs) ----
extern "C" void kernel_launch(void* const* d_in, const int* in_sizes, int n_in,
                              void* d_out, int out_size, void* d_ws, size_t ws_size,
                              hipStream_t stream) {
    const float* data_in = (const float*)d_in[0];
    const int*   neigh   = (const int*)d_in[1];
    const float* weight  = (const float*)d_in[2];
    const float* gamma   = (const float*)d_in[3];
    const float* beta    = (const float*)d_in[4];
    float* out = (float*)d_out;

    int N = in_sizes[1] / KK;
    const int nxblk  = (N + 31) / 32;
    const int ntiles = (N + 31) / 32;
    int nblk = (ntiles + 3) / 4;        // 782 @ N=100k -- all co-resident (<=1024 slots)
    if (nblk > 1024) nblk = 1024;       // grid-stride iters keep correctness beyond
    if (nblk < 1) nblk = 1;

    char* ws = (char*)d_ws;
    size_t halfBytes = (size_t)(N + 1) * 32;                 // 16 bf16 per row
    unsigned short* xLo = (unsigned short*)ws;
    unsigned short* xHi = (unsigned short*)(ws + halfBytes);
    unsigned short* wP0 = (unsigned short*)(ws + 2 * halfBytes);   // PT*1024 bf16
    unsigned short* wP1 = wP0 + PT * 1024;
    float* tot = (float*)(wP1 + PT * 1024);                  // 2048 floats
    int*   bar = (int*)(tot + 2048);                         // 16 slabs x 1024 ints

    prep_k<<<nxblk + PT, 256, 0, stream>>>(data_in, weight, xLo, xHi, wP0, wP1,
                                           tot, bar, N, nxblk);
    convnorm_k<<<dim3(nblk), dim3(256), 0, stream>>>(xLo, xHi, neigh, wP0, wP1,
                                                     gamma, beta, out, tot, bar, N);
}

// Round 12
// 133.422 us; speedup vs baseline: 2.2829x; 1.2537x over previous
//
#include <hip/hip_runtime.h>

#define KK 27

typedef short bf16x8 __attribute__((ext_vector_type(8)));   // 8 bf16 in 4 VGPRs
typedef float f32x4  __attribute__((ext_vector_type(4)));

__device__ inline unsigned short f2bf(float f) {            // RNE fp32 -> bf16
    unsigned u = __float_as_uint(f);
    unsigned r = u + 0x7fffu + ((u >> 16) & 1u);
    return (unsigned short)(r >> 16);
}

// ---- Kernel 1 (fused prep) ----
// blocks [0,nxblk):            x [32][N] fp32 -> xTb [N+1][32] bf16 (row N = zeros)
// blocks [nxblk, nxblk+KK):    weight -> wTb [27][cout=32][cin=32] bf16 (+ zero tot at k==0)
// blocks [nxblk+KK, ...):      neigh [N][27] -> neighT [27][N]  (LDS-staged, both sides
//                              coalesced). Kills conv's 108B-stride divergent idx loads.
__global__ __launch_bounds__(256) void prep_k(const float* __restrict__ in,
                                              const float* __restrict__ w,
                                              const int* __restrict__ neigh,
                                              unsigned short* __restrict__ xTb,
                                              unsigned short* __restrict__ wTb,
                                              int* __restrict__ neighT,
                                              float* __restrict__ tot,
                                              int N, int nxblk, int doT) {
    __shared__ float tile[32][33];
    __shared__ int   nt[64 * KK];          // 6.9 KB neigh staging
    const int b = blockIdx.x;
    if (b < nxblk) {
        int n0 = b * 32;
        int tx = threadIdx.x & 31;
        int ty = threadIdx.x >> 5;  // 0..7
#pragma unroll
        for (int c = ty; c < 32; c += 8) {
            int n = n0 + tx;
            tile[c][tx] = (n < N) ? in[(long)c * N + n] : 0.f;
        }
        __syncthreads();
#pragma unroll
        for (int nn = ty; nn < 32; nn += 8) {
            int n = n0 + nn;
            if (n < N) xTb[(long)n * 32 + tx] = f2bf(tile[tx][nn]);
        }
        if (b == 0 && threadIdx.x < 32) xTb[(long)N * 32 + threadIdx.x] = 0;  // zero row
    } else if (b < nxblk + KK) {
        int k = b - nxblk;
        for (int i = threadIdx.x; i < 1024; i += 256) {
            int cin = i >> 5, cout = i & 31;
            wTb[k * 1024 + cout * 32 + cin] = f2bf(w[k * 1024 + cin * 32 + cout]);
        }
        if (k == 0) {
            for (int i = threadIdx.x; i < 32 * 64; i += 256) tot[i] = 0.f;
        }
    } else if (doT) {
        int t = b - nxblk - KK;            // 64-node transpose tile
        int n0 = t * 64;
        int cnt = N - n0; if (cnt > 64) cnt = 64;
        for (int i = threadIdx.x; i < cnt * KK; i += 256)
            nt[i] = neigh[(long)n0 * KK + i];               // coalesced read
        __syncthreads();
        for (int i = threadIdx.x; i < KK * 64; i += 256) {
            int tap = i >> 6, n = i & 63;                   // coalesced write per tap row
            if (n < cnt) neighT[(long)tap * N + n0 + n] = nt[n * KK + tap];
        }
    }
}

// ---- Kernel 2: MFMA conv (R0 body = best measured, 48.6us) + striped-atomic BN ----
// 1 wave per 32 nodes, 2 gather streams, depth-2 pipeline, plain 27-tap loop.
// TR=1: idx loads from neighT[27][N] -- lanes r16 contiguous -> 2 lines/instruction
// instead of ~16 (the idx stream was ~half the wave's address-divergence work).
// Invalid lanes (node >= N) gather the all-zero row N of xTb.
template <bool TR>
__global__ __launch_bounds__(64, 4) void conv_k(const unsigned short* __restrict__ xTb,
                                                const int* __restrict__ ng,   // [27][N] or [N][27]
                                                const unsigned short* __restrict__ wTb,
                                                float* __restrict__ y,    // [32][N]
                                                float* __restrict__ tot,  // [32][64] striped
                                                int N) {
    __shared__ float ct[32][33];

    const int L    = threadIdx.x;      // 0..63
    const int r16  = L & 15;
    const int quad = L >> 4;           // 0..3
    const int base = blockIdx.x * 32;
    const int n0 = base + r16;
    const int n1 = base + 16 + r16;
    const bool v0 = (n0 < N), v1 = (n1 < N);
    const int  n0c = v0 ? n0 : 0;
    const int  n1c = v1 ? n1 : 0;
    const long nb0 = (long)n0c * KK;
    const long nb1 = (long)n1c * KK;

    auto IDX0 = [&](int k) -> int {
        int j = TR ? ng[(long)k * N + n0c] : ng[nb0 + k];
        return v0 ? j : N;
    };
    auto IDX1 = [&](int k) -> int {
        int j = TR ? ng[(long)k * N + n1c] : ng[nb1 + k];
        return v1 ? j : N;
    };

    f32x4 acc00 = {0.f, 0.f, 0.f, 0.f};
    f32x4 acc01 = acc00, acc10 = acc00, acc11 = acc00;

    int ia = IDX0(0);
    int ib = IDX1(0);
    int ja = IDX0(1);
    int jb = IDX1(1);

    bf16x8 a0 = *(const bf16x8*)(xTb + (long)ia * 32 + quad * 8);
    bf16x8 a1 = *(const bf16x8*)(xTb + (long)ib * 32 + quad * 8);
    bf16x8 b0 = *(const bf16x8*)(wTb + r16 * 32 + quad * 8);
    bf16x8 b1 = *(const bf16x8*)(wTb + (16 + r16) * 32 + quad * 8);

#pragma unroll 1
    for (int k = 0; k < KK; ++k) {
        bf16x8 na0, na1, pb0, pb1;
        if (k < KK - 1) {
            na0 = *(const bf16x8*)(xTb + (long)ja * 32 + quad * 8);
            na1 = *(const bf16x8*)(xTb + (long)jb * 32 + quad * 8);
            const unsigned short* wn = wTb + (k + 1) * 1024;
            pb0 = *(const bf16x8*)(wn + r16 * 32 + quad * 8);
            pb1 = *(const bf16x8*)(wn + (16 + r16) * 32 + quad * 8);
            int kk = (k + 2 < KK) ? (k + 2) : (KK - 1);
            ja = IDX0(kk);
            jb = IDX1(kk);
        }

        acc00 = __builtin_amdgcn_mfma_f32_16x16x32_bf16(a0, b0, acc00, 0, 0, 0);
        acc01 = __builtin_amdgcn_mfma_f32_16x16x32_bf16(a0, b1, acc01, 0, 0, 0);
        acc10 = __builtin_amdgcn_mfma_f32_16x16x32_bf16(a1, b0, acc10, 0, 0, 0);
        acc11 = __builtin_amdgcn_mfma_f32_16x16x32_bf16(a1, b1, acc11, 0, 0, 0);

        if (k < KK - 1) {
            a0 = na0;
            a1 = na1;
            b0 = pb0;
            b1 = pb1;
        }
    }

    // BN partials: sum over this wave's 32 nodes -> striped atomics (32 stripes)
    float s0 = 0.f, q0 = 0.f, s1 = 0.f, q1 = 0.f;
#pragma unroll
    for (int r = 0; r < 4; ++r) {
        s0 += acc00[r] + acc10[r];
        q0 += acc00[r] * acc00[r] + acc10[r] * acc10[r];
        s1 += acc01[r] + acc11[r];
        q1 += acc01[r] * acc01[r] + acc11[r] * acc11[r];
    }
#pragma unroll
    for (int off = 16; off < 64; off <<= 1) {   // reduce across quads (nodes)
        s0 += __shfl_xor(s0, off, 64);
        q0 += __shfl_xor(q0, off, 64);
        s1 += __shfl_xor(s1, off, 64);
        q1 += __shfl_xor(q1, off, 64);
    }
    const int stripe = blockIdx.x & 31;
    if (L < 16) {
        float* tb = tot + stripe * 64;
        atomicAdd(&tb[L],      s0);
        atomicAdd(&tb[L + 16], s1);
        atomicAdd(&tb[L + 32], q0);
        atomicAdd(&tb[L + 48], q1);
    }

    // LDS transpose -> coalesced y stores ([cout][node], 32 contiguous nodes)
#pragma unroll
    for (int r = 0; r < 4; ++r) {
        ct[quad * 4 + r][r16]           = acc00[r];
        ct[quad * 4 + r][16 + r16]      = acc01[r];
        ct[16 + quad * 4 + r][r16]      = acc10[r];
        ct[16 + quad * 4 + r][16 + r16] = acc11[r];
    }
    __syncthreads();
    const int node = L & 31;
    const int half = L >> 5;
    const int gn = base + node;
    if (gn < N) {
#pragma unroll
        for (int i = 0; i < 16; ++i) {
            const int cout = i * 2 + half;
            y[(long)cout * N + gn] = ct[node][cout];
        }
    }
}

// ---- Kernel 3: normalize y in place (stripe-reduce + stats finalize fused) ----
__global__ __launch_bounds__(256) void norm_k(float* __restrict__ y,
                                              const float* __restrict__ tot,
                                              const float* __restrict__ gamma,
                                              const float* __restrict__ beta, int N) {
    const int d = blockIdx.y;
    float sm = 0.f, sq = 0.f;
#pragma unroll
    for (int s = 0; s < 32; ++s) {              // reduce the 32 stripes (8KB, L2-hot)
        sm += tot[s * 64 + d];
        sq += tot[s * 64 + 32 + d];
    }
    const float mean = sm / (float)N;
    const float var  = sq / (float)N - mean * mean;
    const float sc   = gamma[d] * rsqrtf(var + 1e-3f);
    const float sh   = beta[d] - mean * sc;

    int i = blockIdx.x * blockDim.x + threadIdx.x;
    int base = i * 4;
    if (base + 3 < N) {
        float4* p = (float4*)(y + (long)d * N + base);
        float4 v = *p;
        v.x = fmaf(v.x, sc, sh);
        v.y = fmaf(v.y, sc, sh);
        v.z = fmaf(v.z, sc, sh);
        v.w = fmaf(v.w, sc, sh);
        *p = v;
    } else if (base < N) {
        for (int t = base; t < N; ++t) y[(long)d * N + t] = fmaf(y[(long)d * N + t], sc, sh);
    }
}

// ---- launcher: 3 launches, no memset; neigh-transpose only if workspace allows ----
extern "C" void kernel_launch(void* const* d_in, const int* in_sizes, int n_in,
                              void* d_out, int out_size, void* d_ws, size_t ws_size,
                              hipStream_t stream) {
    const float* data_in = (const float*)d_in[0];
    const int*   neigh   = (const int*)d_in[1];
    const float* weight  = (const float*)d_in[2];
    const float* gamma   = (const float*)d_in[3];
    const float* beta    = (const float*)d_in[4];
    float* out = (float*)d_out;

    const int N = in_sizes[1] / KK;
    const int nxblk = (N + 31) / 32;    // x-prep blocks
    const int nblk  = (N + 31) / 32;    // 32 nodes per 1-wave conv block
    const int ntblk = (N + 63) / 64;    // neigh-transpose tiles

    char* ws = (char*)d_ws;
    unsigned short* xTb = (unsigned short*)ws;                            // (N+1)*32 bf16
    unsigned short* wTb = (unsigned short*)(ws + (size_t)(N + 1) * 64);   // 27*1024 bf16
    float* tot = (float*)(ws + (size_t)(N + 1) * 64 + 55296);             // 32*64 floats
    int* neighT = (int*)(ws + (size_t)(N + 1) * 64 + 55296 + 32 * 64 * 4);

    const size_t need = (size_t)(N + 1) * 64 + 55296 + 32 * 64 * 4
                      + (size_t)KK * N * 4;
    const int doT = (ws_size >= need) ? 1 : 0;

    prep_k<<<nxblk + KK + (doT ? ntblk : 0), 256, 0, stream>>>(
        data_in, weight, neigh, xTb, wTb, neighT, tot, N, nxblk, doT);
    if (doT)
        conv_k<true><<<nblk, 64, 0, stream>>>(xTb, neighT, wTb, out, tot, N);
    else
        conv_k<false><<<nblk, 64, 0, stream>>>(xTb, neigh, wTb, out, tot, N);
    dim3 ngrid(((N + 3) / 4 + 255) / 256, 32);
    norm_k<<<ngrid, 256, 0, stream>>>(out, tot, gamma, beta, N);
}